// Round 4
// baseline (197.524 us; speedup 1.0000x reference)
//
#include <hip/hip_runtime.h>

#define DEV static __device__ __forceinline__

typedef float f32x4 __attribute__((ext_vector_type(4)));
typedef __bf16 bf16x8 __attribute__((ext_vector_type(8)));
typedef unsigned short u16x8 __attribute__((ext_vector_type(8)));
typedef unsigned short u16x4 __attribute__((ext_vector_type(4)));

#define MFMA(a, b, c) __builtin_amdgcn_mfma_f32_16x16x32_bf16((a), (b), (c), 0, 0, 0)

// B=8, T=2048, C=1024, H=64
#define TT 2048
#define CE 1024
#define HS 64

// ws layout (ushort elements unless noted)
#define WBT_E 0                   // [3][64 n][1024 k] bf16 (Wq scaled by log2e/32)
#define Q_E   196608              // [B*T][64] bf16
#define K_E   (Q_E + 1048576)
#define VT_E  (K_E + 1048576)     // [B][64 h][2048 t] bf16
#define PO_E  (VT_E + 1048576)    // [4096 slots][64 h][16 row] bf16 partial O
#define PML_E (PO_E + 4194304)    // float [4096][16 row][2] {m,l}  (cast to float*)

DEV unsigned short cvt_bf16(float f) {
    unsigned int u = __builtin_bit_cast(unsigned int, f);
    u += 0x7FFFu + ((u >> 16) & 1u);   // RNE (finite inputs)
    return (unsigned short)(u >> 16);
}

DEV float bf2f(unsigned short v) {
    unsigned int u = ((unsigned int)v) << 16;
    return __builtin_bit_cast(float, u);
}

DEV bf16x8 ld_bf8(const unsigned short* p) {
    union { u16x8 u; bf16x8 b; } v;
    v.u = *(const u16x8*)p;
    return v.b;
}

DEV bf16x8 as_bf8(u16x8 u) {
    union { u16x8 u; bf16x8 b; } v;
    v.u = u;
    return v.b;
}

// ---------------- kernel 1: W fp32 -> bf16 transposed [n][k], coalesced -----
__global__ __launch_bounds__(256) void wconv_kernel(
        const float* __restrict__ Wq, const float* __restrict__ Wk,
        const float* __restrict__ Wv, unsigned short* __restrict__ wbt) {
    __shared__ unsigned short Tr[64 * 72];
    const int blk = blockIdx.x;
    const int head = blk >> 4, kt = blk & 15;
    const int k0 = kt * 64;
    const float* W = (head == 0) ? Wq : ((head == 1) ? Wk : Wv);
    const float sc = (head == 0) ? 0.045084220027780106f : 1.0f;  // log2(e)/32
    const int t = threadIdx.x;
    const int rrow = t >> 4, c4 = (t & 15) * 4;
    for (int i = 0; i < 4; ++i) {
        int krow = rrow + i * 16;
        f32x4 f = *(const f32x4*)(W + (size_t)(k0 + krow) * 64 + c4);
        Tr[(c4 + 0) * 72 + krow] = cvt_bf16(f[0] * sc);
        Tr[(c4 + 1) * 72 + krow] = cvt_bf16(f[1] * sc);
        Tr[(c4 + 2) * 72 + krow] = cvt_bf16(f[2] * sc);
        Tr[(c4 + 3) * 72 + krow] = cvt_bf16(f[3] * sc);
    }
    __syncthreads();
    const int n = t >> 2, off = (t & 3) * 16;
    u16x8 a0 = *(const u16x8*)&Tr[n * 72 + off];
    u16x8 a1 = *(const u16x8*)&Tr[n * 72 + off + 8];
    unsigned short* dst = wbt + head * 65536 + n * 1024 + k0 + off;
    *(u16x8*)dst = a0;
    *(u16x8*)(dst + 8) = a1;
}

// ---------------- kernel 2: projection q,k = x@W; v transposed -> vt --------
// 512 blocks x 256 threads (4 waves). 32 rows/block, 192 cols (wave: 48 cols).
// W B-fragments load DIRECT global->register (no LDS staging), prefetched 1
// step ahead. x staged via double-buffered LDS, one barrier/step.
__global__ __launch_bounds__(256) void proj_kernel(
        const float* __restrict__ x, const unsigned short* __restrict__ wbt,
        unsigned short* __restrict__ qws, unsigned short* __restrict__ kws,
        unsigned short* __restrict__ vtws) {
    __shared__ __align__(16) unsigned short As[2 * 32 * 72];   // x tile [row][k]

    const int t = threadIdx.x;
    const int lane = t & 63, w = t >> 6;
    const int quad = lane >> 4, c = lane & 15;
    const int t0 = blockIdx.x * 32;
    const int xrow = t >> 3, xc = (t & 7) * 8;   // x staging: 8 thr/row

    // W B-frag base: wbt[(w*48 + nt*16 + c)*1024 + ks + kk*32 + quad*8]
    const unsigned short* wbase = wbt + (size_t)(w * 48 + c) * 1024 + quad * 8;

    f32x4 acc[2][3] = {};
    u16x8 wc[3][2], wn[3][2];

    // prologue: stage step 0
    {
        f32x4 f0 = *(const f32x4*)(x + (size_t)(t0 + xrow) * CE + xc);
        f32x4 f1 = *(const f32x4*)(x + (size_t)(t0 + xrow) * CE + xc + 4);
        u16x8 pk;
        for (int j = 0; j < 4; ++j) { pk[j] = cvt_bf16(f0[j]); pk[4 + j] = cvt_bf16(f1[j]); }
        *(u16x8*)&As[xrow * 72 + xc] = pk;
        for (int nt = 0; nt < 3; ++nt)
            for (int kk = 0; kk < 2; ++kk)
                wc[nt][kk] = *(const u16x8*)(wbase + nt * 16384 + kk * 32);
    }
    __syncthreads();

    for (int step = 0; step < 16; ++step) {
        const int pb = step & 1, nb = pb ^ 1;
        const int ksn = ((step + 1) & 15) * 64;   // wraps on last step (discarded)
        // ---- prefetch step+1 (x and W) ----
        f32x4 f0 = *(const f32x4*)(x + (size_t)(t0 + xrow) * CE + ksn + xc);
        f32x4 f1 = *(const f32x4*)(x + (size_t)(t0 + xrow) * CE + ksn + xc + 4);
        for (int nt = 0; nt < 3; ++nt)
            for (int kk = 0; kk < 2; ++kk)
                wn[nt][kk] = *(const u16x8*)(wbase + nt * 16384 + ksn + kk * 32);
        // ---- compute on current buffer ----
        for (int kk = 0; kk < 2; ++kk) {
            bf16x8 a0 = ld_bf8(&As[pb * 2304 + c * 72 + kk * 32 + quad * 8]);
            bf16x8 a1 = ld_bf8(&As[pb * 2304 + (16 + c) * 72 + kk * 32 + quad * 8]);
            for (int nt = 0; nt < 3; ++nt) {
                bf16x8 bb = as_bf8(wc[nt][kk]);
                acc[0][nt] = MFMA(a0, bb, acc[0][nt]);
                acc[1][nt] = MFMA(a1, bb, acc[1][nt]);
            }
        }
        // ---- stash prefetched x; rotate W regs ----
        {
            u16x8 pk;
            for (int j = 0; j < 4; ++j) { pk[j] = cvt_bf16(f0[j]); pk[4 + j] = cvt_bf16(f1[j]); }
            *(u16x8*)&As[nb * 2304 + xrow * 72 + xc] = pk;
        }
        for (int nt = 0; nt < 3; ++nt)
            for (int kk = 0; kk < 2; ++kk) wc[nt][kk] = wn[nt][kk];
        __syncthreads();
    }

    // epilogue: q,k direct; v transposed via LDS (64 h x 32 t, stride 48 ok)
    unsigned short* TT2 = As;
    for (int mt = 0; mt < 2; ++mt)
        for (int nt = 0; nt < 3; ++nt) {
            f32x4 a = acc[mt][nt];
            int col = w * 48 + nt * 16 + c;
            for (int r = 0; r < 4; ++r) {
                int row = mt * 16 + quad * 4 + r;
                size_t tg = (size_t)(t0 + row);
                unsigned short hv = cvt_bf16(a[r]);
                if (col < 64)       qws[tg * HS + col] = hv;
                else if (col < 128) kws[tg * HS + col - 64] = hv;
                else                TT2[(col - 128) * 48 + row] = hv;
            }
        }
    __syncthreads();
    {
        int h = t >> 2, off = (t & 3) * 8;
        u16x8 v = *(const u16x8*)&TT2[h * 48 + off];
        int b = t0 >> 11, tl0 = t0 & 2047;
        *(u16x8*)(vtws + (size_t)(b * 64 + h) * TT + tl0 + off) = v;
    }
}

// ---------------- kernel 3: flash partial, 1 wave/block, kv-split -----------
// grid 4096: b=blk>>9, qt=(blk>>2)&127 (16 q-rows), sp=blk&3 (512-kv split).
// No barriers. K/V B-frags direct global->reg, prefetched one chunk ahead.
// Outputs unnormalized O (bf16) + (m,l) per row.
__global__ __launch_bounds__(64) void flash_kernel(
        const unsigned short* __restrict__ qws, const unsigned short* __restrict__ kws,
        const unsigned short* __restrict__ vtws, const int* __restrict__ pmask,
        unsigned short* __restrict__ pO, float* __restrict__ pml) {
    __shared__ __align__(16) unsigned short Ps[16 * 40];  // per-wave P scratch

    const int blk = blockIdx.x;
    const int sp = blk & 3, qt = (blk >> 2) & 127, b = blk >> 9;
    const int ns = (qt >> 5) + 1;                 // ceil((qt+1)/32)
    if (sp >= ns) return;
    const int kvlen = qt * 16 + 16;
    const int kvs = sp * 512;
    const int kve = (kvs + 512 < kvlen) ? kvs + 512 : kvlen;
    const int nch = (kve - kvs + 31) >> 5;
    const int lane = threadIdx.x;
    const int quad = lane >> 4, c = lane & 15;
    const float NEGINF = -__builtin_inff();

    const unsigned short* kbase = kws + (size_t)(b * TT + c) * HS + quad * 8;
    const unsigned short* vbase = vtws + (size_t)(b * 64 + c) * TT + quad * 8;

    // Q fragments (m=c, k=kk*32+quad*8+j)
    bf16x8 qf[2];
    for (int kk = 0; kk < 2; ++kk)
        qf[kk] = ld_bf8(qws + (size_t)(b * TT + qt * 16 + c) * HS + kk * 32 + quad * 8);

    // prefetch chunk 0
    u16x8 kc[2][2], vc[4], kn[2][2], vn[4];
    int pmc[2], pmn[2];
    for (int nt = 0; nt < 2; ++nt) {
        for (int kk = 0; kk < 2; ++kk)
            kc[nt][kk] = *(const u16x8*)(kbase + (size_t)(kvs + nt * 16) * HS + kk * 32);
        pmc[nt] = pmask[b * TT + kvs + nt * 16 + c];
    }
    for (int ht = 0; ht < 4; ++ht)
        vc[ht] = *(const u16x8*)(vbase + (size_t)(ht * 16) * TT + kvs);

    f32x4 o[4] = {};
    float m_run[4], l_run[4];
    for (int r = 0; r < 4; ++r) { m_run[r] = NEGINF; l_run[r] = 0.0f; }

    for (int ch = 0; ch < nch; ++ch) {
        const int kv0 = kvs + ch * 32;
        const int kvn = (ch + 1 < nch) ? kv0 + 32 : kv0;   // last: dummy reload
        // ---- prefetch next chunk ----
        for (int nt = 0; nt < 2; ++nt) {
            for (int kk = 0; kk < 2; ++kk)
                kn[nt][kk] = *(const u16x8*)(kbase + (size_t)(kvn + nt * 16) * HS + kk * 32);
            pmn[nt] = pmask[b * TT + kvn + nt * 16 + c];
        }
        for (int ht = 0; ht < 4; ++ht)
            vn[ht] = *(const u16x8*)(vbase + (size_t)(ht * 16) * TT + kvn);

        // ---- S = Q K^T ----
        f32x4 s4[2] = {};
        for (int kk = 0; kk < 2; ++kk)
            for (int nt = 0; nt < 2; ++nt)
                s4[nt] = MFMA(qf[kk], as_bf8(kc[nt][kk]), s4[nt]);

        // ---- masking: pad always; causal on the diagonal chunk ----
        if (sp == ns - 1 && ch == nch - 1) {
            for (int nt = 0; nt < 2; ++nt) {
                int col = kv0 + nt * 16 + c;
                for (int r = 0; r < 4; ++r) {
                    int row = qt * 16 + quad * 4 + r;
                    if (pmc[nt] == 0 || col > row) s4[nt][r] = NEGINF;
                }
            }
        } else {
            for (int nt = 0; nt < 2; ++nt)
                if (pmc[nt] == 0)
                    for (int r = 0; r < 4; ++r) s4[nt][r] = NEGINF;
        }

        // ---- online softmax (base-2); rows in 16-lane groups ----
        float al[4];
        for (int r = 0; r < 4; ++r) {
            float mx = fmaxf(s4[0][r], s4[1][r]);
            mx = fmaxf(mx, __shfl_xor(mx, 1, 64));
            mx = fmaxf(mx, __shfl_xor(mx, 2, 64));
            mx = fmaxf(mx, __shfl_xor(mx, 4, 64));
            mx = fmaxf(mx, __shfl_xor(mx, 8, 64));
            float mnew = fmaxf(m_run[r], mx);
            al[r] = (mnew == NEGINF) ? 1.0f : exp2f(m_run[r] - mnew);
            m_run[r] = mnew;
        }
        for (int nt = 0; nt < 2; ++nt)
            for (int r = 0; r < 4; ++r)
                s4[nt][r] = (s4[nt][r] == NEGINF) ? 0.0f : exp2f(s4[nt][r] - m_run[r]);
        for (int r = 0; r < 4; ++r) {
            float rs = s4[0][r] + s4[1][r];
            rs += __shfl_xor(rs, 1, 64);
            rs += __shfl_xor(rs, 2, 64);
            rs += __shfl_xor(rs, 4, 64);
            rs += __shfl_xor(rs, 8, 64);
            l_run[r] = l_run[r] * al[r] + rs;
        }
        for (int ht = 0; ht < 4; ++ht)
            for (int r = 0; r < 4; ++r) o[ht][r] *= al[r];

        // ---- P: C-layout -> LDS -> A-layout (wave-private, no barrier) ----
        for (int nt = 0; nt < 2; ++nt)
            for (int r = 0; r < 4; ++r)
                Ps[(quad * 4 + r) * 40 + nt * 16 + c] = cvt_bf16(s4[nt][r]);
        bf16x8 pa = ld_bf8(&Ps[c * 40 + quad * 8]);

        // ---- O += P V ----
        for (int ht = 0; ht < 4; ++ht)
            o[ht] = MFMA(pa, as_bf8(vc[ht]), o[ht]);

        // rotate prefetch
        for (int nt = 0; nt < 2; ++nt) {
            for (int kk = 0; kk < 2; ++kk) kc[nt][kk] = kn[nt][kk];
            pmc[nt] = pmn[nt];
        }
        for (int ht = 0; ht < 4; ++ht) vc[ht] = vn[ht];
    }

    // ---- store partial: O bf16 [slot][h][row], (m,l) fp32 [slot][row] ----
    const int slot = blk;
    unsigned short* po = pO + (size_t)slot * 1024;
    for (int ht = 0; ht < 4; ++ht) {
        u16x4 pk;
        for (int r = 0; r < 4; ++r) pk[r] = cvt_bf16(o[ht][r]);
        *(u16x4*)(po + (ht * 16 + c) * 16 + quad * 4) = pk;
    }
    if (c == 0)
        for (int r = 0; r < 4; ++r) {
            pml[(size_t)slot * 32 + (quad * 4 + r) * 2] = m_run[r];
            pml[(size_t)slot * 32 + (quad * 4 + r) * 2 + 1] = l_run[r];
        }
}

// ---------------- kernel 4: combine splits -> final output ------------------
// 1024 blocks (b,qt) x 256 thr: rowg = t>>6 (4 rows each), h = t&63.
__global__ __launch_bounds__(256) void combine_kernel(
        const unsigned short* __restrict__ pO, const float* __restrict__ pml,
        float* __restrict__ out) {
    const int blk = blockIdx.x;
    const int b = blk >> 7, qt = blk & 127;
    const int ns = (qt >> 5) + 1;
    const int base = blk * 4;
    const int t = threadIdx.x;
    const int rowg = t >> 6, h = t & 63;

    float msp[4][4], lsp[4][4];
    for (int sp = 0; sp < ns; ++sp)
        for (int r = 0; r < 4; ++r) {
            msp[sp][r] = pml[(size_t)(base + sp) * 32 + (rowg * 4 + r) * 2];
            lsp[sp][r] = pml[(size_t)(base + sp) * 32 + (rowg * 4 + r) * 2 + 1];
        }
    float M[4];
    for (int r = 0; r < 4; ++r) {
        M[r] = msp[0][r];
        for (int sp = 1; sp < ns; ++sp) M[r] = fmaxf(M[r], msp[sp][r]);
    }
    float acc[4] = {}, den[4] = {};
    for (int sp = 0; sp < ns; ++sp) {
        u16x4 ov = *(const u16x4*)(pO + (size_t)(base + sp) * 1024 + h * 16 + rowg * 4);
        for (int r = 0; r < 4; ++r) {
            float wgt = exp2f(msp[sp][r] - M[r]);
            den[r] += lsp[sp][r] * wgt;
            acc[r] += bf2f(ov[r]) * wgt;
        }
    }
    for (int r = 0; r < 4; ++r)
        out[(size_t)(b * TT + qt * 16 + rowg * 4 + r) * HS + h] = acc[r] / den[r];
}

extern "C" void kernel_launch(void* const* d_in, const int* in_sizes, int n_in,
                              void* d_out, int out_size, void* d_ws, size_t ws_size,
                              hipStream_t stream) {
    const float* x  = (const float*)d_in[0];
    const int* pm   = (const int*)d_in[1];
    const float* Wq = (const float*)d_in[2];
    const float* Wk = (const float*)d_in[3];
    const float* Wv = (const float*)d_in[4];
    float* out = (float*)d_out;

    unsigned short* wsu  = (unsigned short*)d_ws;
    unsigned short* wbt  = wsu + WBT_E;
    unsigned short* qws  = wsu + Q_E;
    unsigned short* kws  = wsu + K_E;
    unsigned short* vtws = wsu + VT_E;
    unsigned short* pO   = wsu + PO_E;
    float* pml           = (float*)(wsu + PML_E);

    wconv_kernel<<<48, 256, 0, stream>>>(Wq, Wk, Wv, wbt);
    proj_kernel<<<512, 256, 0, stream>>>(x, wbt, qws, kws, vtws);
    flash_kernel<<<4096, 64, 0, stream>>>(qws, kws, vtws, pm, pO, pml);
    combine_kernel<<<1024, 256, 0, stream>>>(pO, pml, out);
}